// Round 6
// baseline (59690.790 us; speedup 1.0000x reference)
//
#include <hip/hip_runtime.h>

// ---------------------------------------------------------------------------
// ROUND 6: pure-fp32 NAIVE pipeline (no MFMA, no bf16, no global_load_lds).
// Rounds 2-5 produced garbage in both staging variants and both output
// dtypes => compute bug somewhere in the MFMA stack that inspection can't
// find. Establish a green baseline with obviously-correct code, then
// re-introduce fast stages one per round (differential bisection).
// Reference: v=(x@Wv.T+bv), k=..., q=(x@Wq.T+bq); energy[n,h,q,l]=q.k;
// masked->0; *1/sqrt(E) (folded into Q); out[n,q,e]=sum_h sum_l P*v;
// final = out@Wo.T + bo. Output fp32 (harness contract: ref dtype fp32).
// Diagnostics via absmax channel: fill 1000 => in_sizes mismatch,
// fill 2000 => ws_size too small. need = 56.6MB.
// ---------------------------------------------------------------------------

#define RS 0.04419417382415922f  // 1/sqrt(512)

__global__ void k_fill(float* p, int n, float v) {
  int i = blockIdx.x * blockDim.x + threadIdx.x;
  int stride = gridDim.x * blockDim.x;
  for (; i < n; i += stride) p[i] = v;
}

// Y[l][o] = (sum_k X[l][k]*W[o][k] + b[o]) * scale   (l<1024, o<4096, k<512)
__global__ __launch_bounds__(256) void k_proj(const float* __restrict__ X,
                                              const float* __restrict__ W,
                                              const float* __restrict__ b,
                                              float scale,
                                              float* __restrict__ Y) {
  __shared__ float xs[512];
  int l = blockIdx.x;
  const float* xr = X + (size_t)l * 512;
  for (int i = threadIdx.x; i < 512; i += 256) xs[i] = xr[i];
  __syncthreads();
  for (int j = 0; j < 16; ++j) {
    int o = j * 256 + threadIdx.x;
    const float* wr = W + (size_t)o * 512;
    float acc = 0.f;
#pragma unroll 8
    for (int k = 0; k < 512; ++k) acc += xs[k] * wr[k];
    Y[(size_t)l * 4096 + o] = (acc + b[o]) * scale;
  }
}

// P1[q][l] = mask[q][l] ? dot(Qn[q][h*512+:], Kn[l][h*512+:]) : 0
__global__ __launch_bounds__(256) void k_energy(const float* __restrict__ Qn,
                                                const float* __restrict__ Kn,
                                                const int* __restrict__ mask,
                                                int h, float* __restrict__ P1) {
  __shared__ float qs[512];
  int q = blockIdx.x;
  const float* qr = Qn + (size_t)q * 4096 + h * 512;
  for (int i = threadIdx.x; i < 512; i += 256) qs[i] = qr[i];
  __syncthreads();
  for (int j = 0; j < 4; ++j) {
    int l = j * 256 + threadIdx.x;
    const float* kr = Kn + (size_t)l * 4096 + h * 512;
    float acc = 0.f;
#pragma unroll 8
    for (int k = 0; k < 512; ++k) acc += qs[k] * kr[k];
    P1[(size_t)q * 1024 + l] = mask[(size_t)q * 1024 + l] ? acc : 0.f;
  }
}

// Atn[q][e] (h==0 ? = : +=) sum_l P1[q][l] * Vn[l][h*512+e]
__global__ __launch_bounds__(256) void k_pv(const float* __restrict__ P1,
                                            const float* __restrict__ Vn,
                                            int h, float* __restrict__ Atn) {
  __shared__ float ps[1024];
  int q = blockIdx.x;
  const float* pr = P1 + (size_t)q * 1024;
  for (int i = threadIdx.x; i < 1024; i += 256) ps[i] = pr[i];
  __syncthreads();
  for (int j = 0; j < 2; ++j) {
    int e = j * 256 + threadIdx.x;
    const float* vb = Vn + h * 512 + e;
    float acc = 0.f;
    for (int l = 0; l < 1024; ++l) acc += ps[l] * vb[(size_t)l * 4096];
    float* dst = &Atn[(size_t)q * 512 + e];
    *dst = (h == 0 ? 0.f : *dst) + acc;
  }
}

// out[q][o] = sum_k Atn[q][k]*Wo[o][k] + bo[o]
__global__ __launch_bounds__(256) void k_final(const float* __restrict__ Atn,
                                               const float* __restrict__ Wo,
                                               const float* __restrict__ bo,
                                               float* __restrict__ out) {
  __shared__ float as_[512];
  int q = blockIdx.x;
  const float* ar = Atn + (size_t)q * 512;
  for (int i = threadIdx.x; i < 512; i += 256) as_[i] = ar[i];
  __syncthreads();
  for (int j = 0; j < 2; ++j) {
    int o = j * 256 + threadIdx.x;
    const float* wr = Wo + (size_t)o * 512;
    float acc = 0.f;
#pragma unroll 8
    for (int k = 0; k < 512; ++k) acc += as_[k] * wr[k];
    out[(size_t)q * 512 + o] = acc + bo[o];
  }
}

extern "C" void kernel_launch(void* const* d_in, const int* in_sizes, int n_in,
                              void* d_out, int out_size, void* d_ws,
                              size_t ws_size, hipStream_t stream) {
  const float* values = (const float*)d_in[0];
  const float* keys = (const float*)d_in[1];
  const float* query = (const float*)d_in[2];
  const int* maskI = (const int*)d_in[4];
  const float* Wv = (const float*)d_in[5];
  const float* bv = (const float*)d_in[6];
  const float* Wk = (const float*)d_in[7];
  const float* bk = (const float*)d_in[8];
  const float* Wq = (const float*)d_in[9];
  const float* bq = (const float*)d_in[10];
  const float* Wo = (const float*)d_in[11];
  const float* bo = (const float*)d_in[12];
  float* dout = (float*)d_out;

  // ---- diagnostic: input order/shape check (fill 1000 on mismatch) ----
  const int exp_sizes[13] = {4194304, 4194304, 4194304, 1024, 8388608,
                             2097152, 4096,    2097152, 4096, 2097152,
                             4096,    262144,  512};
  bool ok = (n_in == 13);
  if (ok)
    for (int i = 0; i < 13; ++i)
      if (in_sizes[i] != exp_sizes[i]) ok = false;
  if (!ok) {
    k_fill<<<512, 256, 0, stream>>>(dout, out_size, 1000.f);
    return;
  }

  // ---- workspace: Qn,Kn,Vn (16.8MB each) + P1 (4.2MB) + Atn (2.1MB) ----
  const size_t SQN = 16777216;  // 1024*4096 fp32
  const size_t SP1 = 4194304;   // 1024*1024 fp32
  const size_t need = 3 * SQN + SP1 + 2097152;
  if (ws_size < need) {
    k_fill<<<512, 256, 0, stream>>>(dout, out_size, 2000.f);
    return;
  }
  char* w = (char*)d_ws;
  float* Qn = (float*)(w);
  float* Kn = (float*)(w + SQN);
  float* Vn = (float*)(w + 2 * SQN);
  float* P1 = (float*)(w + 3 * SQN);
  float* Atn = (float*)(w + 3 * SQN + SP1);

  for (int n = 0; n < 8; ++n) {
    const size_t xoff = (size_t)n * 1024 * 512;
    k_proj<<<1024, 256, 0, stream>>>(values + xoff, Wv, bv, 1.0f, Vn);
    k_proj<<<1024, 256, 0, stream>>>(keys + xoff, Wk, bk, 1.0f, Kn);
    k_proj<<<1024, 256, 0, stream>>>(query + xoff, Wq, bq, RS, Qn);
    for (int h = 0; h < 8; ++h) {
      k_energy<<<1024, 256, 0, stream>>>(Qn, Kn,
                                         maskI + (size_t)n * 1024 * 1024, h,
                                         P1);
      k_pv<<<1024, 256, 0, stream>>>(P1, Vn, h, Atn);
    }
    k_final<<<1024, 256, 0, stream>>>(Atn, Wo, bo,
                                      dout + (size_t)n * 1024 * 512);
  }
}